// Round 9
// baseline (184.066 us; speedup 1.0000x reference)
//
#include <hip/hip_runtime.h>
#include <hip/hip_bf16.h>

// ============================================================================
// indices ∈ [0,64) => backbone + theta have only 64 distinct rows. Compute
// per-class (7 MB, L2-resident), bucket batches by class, run only the tiny
// per-batch MLPs with class-shared weights.
// R9: func v10 — WAVE-SYNCHRONOUS. All prior designs (41-65us) were bound by
// block-wide barriers draining every wave against LDS/L2 latency ~13x/pass.
// Now: 1 block/CU (grid 256, LDS 150KB: full fp32 theta 108.6KB staged ONCE +
// per-wave private scratch), each wave runs its 8-batch tiles end-to-end with
// ZERO barriers (intra-wave LDS ordering = lockstep + compiler lgkmcnt).
// 2col x 8batch register tile -> 16 FMA per b64 weight read. W3f transposed
// at stage time for b128 f-L3 reads.
// ============================================================================

#define LEAKY 0.2f
#define NCLS 64
#define B_TOT 8192
#define NSLICE 4

// theta_e (per class, 5456 fl): W1e[0,128) b1e[128,192) W2e[192,4288)
//   b2e[4288,4352) W3e[4352,5376) b3e[5376,5392)
// theta_f (per class, 21768 fl): W1f[0,4096) b1f[4096,4224) W2f[4224,20608)
//   b2f[20608,20736) W3f[20736,21760) b3f[21760,21768)
// LDS wl layout: te[0..5392) -> wl[0..5392); tf[0..20736) -> wl[5392..26128);
//   W3fT[c][k] -> wl[26128 + c*128 + k]; b3f -> wl[27152..27160)

__device__ __forceinline__ float lrelu(float x) { return x >= 0.f ? x : LEAKY * x; }

// ---------------------------------------------------------------------------
// K1: blocks 0..63: fused backbone for class c. block 64: bucket. 1024 thr.
// ---------------------------------------------------------------------------
__global__ __launch_bounds__(1024) void backbone_bucket_kernel(
    const float* __restrict__ maps,
    const float* __restrict__ fc1_w, const float* __restrict__ fc1_b,
    const float* __restrict__ fc2_w, const float* __restrict__ fc2_b,
    const float* __restrict__ fc3_w, const float* __restrict__ fc3_b,
    const float* __restrict__ bn_w,  const float* __restrict__ bn_b,
    float* __restrict__ z,
    const int* __restrict__ idx, int* __restrict__ counts,
    int* __restrict__ offsets, int* __restrict__ perm)
{
    __shared__ float m[1024];
    __shared__ __align__(16) float4 red4[1024];
    __shared__ __align__(16) float h1[256];
    __shared__ __align__(16) float h2[128];
    __shared__ __align__(16) float h3[128];
    __shared__ int cnt[16][64];
    __shared__ int wcur[16][64];

    const int t = threadIdx.x;

    if (blockIdx.x == 64) {
        const int w = t >> 6;
        cnt[w][t & 63] = 0;
        __syncthreads();
        int my[8];
#pragma unroll
        for (int r = 0; r < 8; ++r) {
            my[r] = idx[r * 1024 + t];
            atomicAdd(&cnt[w][my[r]], 1);
        }
        __syncthreads();
        if (t < 64) {
            int run = 0;
#pragma unroll
            for (int w2 = 0; w2 < 16; ++w2) {
                const int v = cnt[w2][t];
                wcur[w2][t] = run;
                run += v;
            }
            counts[t] = run;
            int x = run;
            for (int d = 1; d < 64; d <<= 1) {
                const int y = __shfl_up(x, d, 64);
                if (t >= d) x += y;
            }
            const int basec = x - run;
            offsets[t] = basec;
#pragma unroll
            for (int w2 = 0; w2 < 16; ++w2) wcur[w2][t] += basec;
        }
        __syncthreads();
#pragma unroll
        for (int r = 0; r < 8; ++r) {
            const int p = atomicAdd(&wcur[w][my[r]], 1);
            perm[p] = r * 1024 + t;
        }
        return;
    }

    const int c = blockIdx.x;
    m[t] = maps[(size_t)c * 1024 + t];
    __syncthreads();

    // fc1: 1024 -> 256 (leaky)
    {
        const int og = t & 63, ks = t >> 6;
        const float* wp = fc1_w + og * 4;
        float4 acc = {0.f, 0.f, 0.f, 0.f};
#pragma unroll 8
        for (int i = 0; i < 64; ++i) {
            const int k = ks * 64 + i;
            const float mk = m[k];
            const float4 w = *(const float4*)&wp[(size_t)k * 256];
            acc.x += mk * w.x; acc.y += mk * w.y;
            acc.z += mk * w.z; acc.w += mk * w.w;
        }
        red4[t] = acc;
    }
    __syncthreads();
    if (t < 64) {
        float4 a = *(const float4*)&fc1_b[t * 4];
#pragma unroll
        for (int r = 0; r < 16; ++r) {
            const float4 v = red4[r * 64 + t];
            a.x += v.x; a.y += v.y; a.z += v.z; a.w += v.w;
        }
        a.x = lrelu(a.x); a.y = lrelu(a.y); a.z = lrelu(a.z); a.w = lrelu(a.w);
        *(float4*)&h1[t * 4] = a;
    }
    __syncthreads();
    // fc2: 256 -> 128 (leaky)
    {
        const int og = t & 31, ks = t >> 5;
        float4 acc = {0.f, 0.f, 0.f, 0.f};
#pragma unroll
        for (int i = 0; i < 8; ++i) {
            const int k = ks * 8 + i;
            const float hk = h1[k];
            const float4 w = *(const float4*)&fc2_w[k * 128 + og * 4];
            acc.x += hk * w.x; acc.y += hk * w.y;
            acc.z += hk * w.z; acc.w += hk * w.w;
        }
        red4[t] = acc;
    }
    __syncthreads();
    if (t < 32) {
        float4 a = *(const float4*)&fc2_b[t * 4];
#pragma unroll
        for (int r = 0; r < 32; ++r) {
            const float4 v = red4[r * 32 + t];
            a.x += v.x; a.y += v.y; a.z += v.z; a.w += v.w;
        }
        a.x = lrelu(a.x); a.y = lrelu(a.y); a.z = lrelu(a.z); a.w = lrelu(a.w);
        *(float4*)&h2[t * 4] = a;
    }
    __syncthreads();
    // fc3: 128 -> 128 (leaky)
    {
        const int og = t & 31, ks = t >> 5;
        float4 acc = {0.f, 0.f, 0.f, 0.f};
#pragma unroll
        for (int i = 0; i < 4; ++i) {
            const int k = ks * 4 + i;
            const float hk = h2[k];
            const float4 w = *(const float4*)&fc3_w[k * 128 + og * 4];
            acc.x += hk * w.x; acc.y += hk * w.y;
            acc.z += hk * w.z; acc.w += hk * w.w;
        }
        red4[t] = acc;
    }
    __syncthreads();
    if (t < 32) {
        float4 a = *(const float4*)&fc3_b[t * 4];
#pragma unroll
        for (int r = 0; r < 32; ++r) {
            const float4 v = red4[r * 32 + t];
            a.x += v.x; a.y += v.y; a.z += v.z; a.w += v.w;
        }
        a.x = lrelu(a.x); a.y = lrelu(a.y); a.z = lrelu(a.z); a.w = lrelu(a.w);
        *(float4*)&h3[t * 4] = a;
    }
    __syncthreads();
    // bn: 128 -> 32
    {
        const int og = t & 7, ks = t >> 3;
        const float hk = h3[ks];
        const float4 w = *(const float4*)&bn_w[ks * 32 + og * 4];
        float4 acc;
        acc.x = hk * w.x; acc.y = hk * w.y; acc.z = hk * w.z; acc.w = hk * w.w;
        red4[t] = acc;
    }
    __syncthreads();
    if (t < 8) {
        float4 a = *(const float4*)&bn_b[t * 4];
#pragma unroll
        for (int r = 0; r < 128; ++r) {
            const float4 v = red4[r * 8 + t];
            a.x += v.x; a.y += v.y; a.z += v.z; a.w += v.w;
        }
        *(float4*)&z[c * 32 + t * 4] = a;
    }
}

// ---------------------------------------------------------------------------
// K2: theta, grid (107, 8): block owns 256 cols x 8 classes. Weights in regs.
// ---------------------------------------------------------------------------
__global__ __launch_bounds__(256) void theta_kernel(
    const float* __restrict__ z,
    const float* __restrict__ e_w, const float* __restrict__ e_b,
    const float* __restrict__ f_w, const float* __restrict__ f_b,
    float* __restrict__ th_e, float* __restrict__ th_f)
{
    __shared__ __align__(16) float zl[2048];
    const int t = threadIdx.x;
    ((float4*)zl)[t]       = ((const float4*)z)[t];
    ((float4*)zl)[t + 256] = ((const float4*)z)[t + 256];
    __syncthreads();

    int j = blockIdx.x * 256 + t;
    const int cbase = blockIdx.y * 8;
    const float* wbase;
    float* op;
    int stride;
    float bias;
    if (j < 5456) {
        wbase = e_w + j; bias = e_b[j]; op = th_e + j; stride = 5456;
    } else {
        const int jj = j - 5456;
        if (jj >= 21768) return;
        wbase = f_w + jj; bias = f_b[jj]; op = th_f + jj; stride = 21768;
    }
    float wk[32];
#pragma unroll
    for (int k = 0; k < 32; ++k) wk[k] = wbase[(size_t)k * stride];

#pragma unroll
    for (int cc = 0; cc < 8; cc += 4) {
        const int c0 = cbase + cc;
        float a0 = bias, a1 = bias, a2 = bias, a3 = bias;
#pragma unroll
        for (int k4 = 0; k4 < 8; ++k4) {
            const float4 z0 = *(const float4*)&zl[(c0 + 0) * 32 + k4 * 4];
            const float4 z1 = *(const float4*)&zl[(c0 + 1) * 32 + k4 * 4];
            const float4 z2 = *(const float4*)&zl[(c0 + 2) * 32 + k4 * 4];
            const float4 z3 = *(const float4*)&zl[(c0 + 3) * 32 + k4 * 4];
            const float w0 = wk[k4 * 4], w1 = wk[k4 * 4 + 1];
            const float w2 = wk[k4 * 4 + 2], w3 = wk[k4 * 4 + 3];
            a0 += z0.x * w0 + z0.y * w1 + z0.z * w2 + z0.w * w3;
            a1 += z1.x * w0 + z1.y * w1 + z1.z * w2 + z1.w * w3;
            a2 += z2.x * w0 + z2.y * w1 + z2.z * w2 + z2.w * w3;
            a3 += z3.x * w0 + z3.y * w1 + z3.z * w2 + z3.w * w3;
        }
        op[(size_t)(c0 + 0) * stride] = a0;
        op[(size_t)(c0 + 1) * stride] = a1;
        op[(size_t)(c0 + 2) * stride] = a2;
        op[(size_t)(c0 + 3) * stride] = a3;
    }
}

// ---------------------------------------------------------------------------
// K3: func v10. grid (64, 4) = 256 blocks (1/CU), 256 thr (4 waves).
// Full class theta fp32 in LDS (staged once, ONE barrier); each wave then
// processes 8-batch tiles independently, barrier-free, via private scratch:
//   A (1152 fl): e-acts [col][eval] stride 17, later sG2 [b][k] stride 132
//   B (1152 fl): e-L2 out [feat][eval] stride 17, later sF [k][b] stride 9
//   Z (288 fl):  states (32 fl), later zf [k][b] stride 9
// ---------------------------------------------------------------------------
__global__ __launch_bounds__(256, 1) void func_kernel(
    const float* __restrict__ states,
    const float* __restrict__ th_e_all, const float* __restrict__ th_f_all,
    const int* __restrict__ counts, const int* __restrict__ offsets,
    const int* __restrict__ perm, float* __restrict__ out)
{
    __shared__ __align__(16) float wl[27160];    // 108.6 KB class weights
    __shared__ __align__(16) float sc[10368];    // 4 x 2592 per-wave scratch

    const int c = blockIdx.x;
    const int s = blockIdx.y;
    const int nb   = counts[c];
    const int base = offsets[c];
    const int chunk = (nb + NSLICE - 1) / NSLICE;
    const int k0 = s * chunk;
    const int k1 = (nb < k0 + chunk) ? nb : (k0 + chunk);
    const int cntq = (k1 > k0) ? (k1 - k0) : 0;
    if (cntq == 0) return;

    const float* te = th_e_all + (size_t)c * 5456;
    const float* tf = th_f_all + (size_t)c * 21768;

    const int t = threadIdx.x;

    // ---- stage full theta (one barrier total) ----
    for (int j = t * 4; j < 5392; j += 1024)
        *(float4*)&wl[j] = *(const float4*)&te[j];
    for (int j = t * 4; j < 20736; j += 1024)
        *(float4*)&wl[5392 + j] = *(const float4*)&tf[j];
    for (int i = t; i < 1024; i += 256) {          // W3f -> W3fT[c][k]
        const int k = i >> 3, cc = i & 7;
        wl[26128 + cc * 128 + k] = tf[20736 + i];
    }
    if (t < 8) wl[27152 + t] = tf[21760 + t];
    __syncthreads();

    const int w    = t >> 6;
    const int lane = t & 63;
    float* A = sc + w * 2592;
    float* B = A + 1152;
    float* Z = B + 1152;

    // lane roles
    const int eg  = lane >> 5;          // e: eval group (8 evals)
    const int cp  = lane & 31;          // e: col pair (cols 2cp, 2cp+1)
    const int ev  = lane & 15;          // e-L3: eval
    const int cg  = lane >> 4;          // e-L3: col quad (cg*4..)
    const int fcp = lane;               // f: col pair (2fcp, 2fcp+1)
    const int fb  = lane & 7;           // f-L3: batch
    const int fc  = lane >> 3;          // f-L3: col

    for (int q = w * 8; q < cntq; q += 32) {
        // ---- load 8 batches' states into Z[0..32) (lanes 0..7) ----
        if (lane < 8) {
            const int kk = q + lane;
            const int bi = (kk < cntq) ? perm[base + k0 + kk] : 0;
            *(float4*)&Z[lane * 4] = *(const float4*)&states[(size_t)bi * 4];
        }

        // ---- e-L1: 2 -> 64 (leaky). eval = eg*8 + b (eg: 0=S, 1=G) ----
        {
            const float2 w0 = *(const float2*)&wl[cp * 2];
            const float2 w1 = *(const float2*)&wl[64 + cp * 2];
            const float2 bb = *(const float2*)&wl[128 + cp * 2];
            float o0[8], o1[8];
#pragma unroll
            for (int b = 0; b < 8; ++b) {
                const float2 sv = *(const float2*)&Z[b * 4 + eg * 2];
                o0[b] = lrelu(sv.x * w0.x + sv.y * w1.x + bb.x);
                o1[b] = lrelu(sv.x * w0.y + sv.y * w1.y + bb.y);
            }
            *(float4*)&A[(cp * 2 + 0) * 17 + eg * 8]     = float4{o0[0], o0[1], o0[2], o0[3]};
            *(float4*)&A[(cp * 2 + 0) * 17 + eg * 8 + 4] = float4{o0[4], o0[5], o0[6], o0[7]};
            *(float4*)&A[(cp * 2 + 1) * 17 + eg * 8]     = float4{o1[0], o1[1], o1[2], o1[3]};
            *(float4*)&A[(cp * 2 + 1) * 17 + eg * 8 + 4] = float4{o1[4], o1[5], o1[6], o1[7]};
        }

        // ---- e-L2: 64 -> 64 (leaky) ----
        {
            float a0[8] = {0, 0, 0, 0, 0, 0, 0, 0};
            float a1[8] = {0, 0, 0, 0, 0, 0, 0, 0};
#pragma unroll 8
            for (int k = 0; k < 64; ++k) {
                const float2 wv = *(const float2*)&wl[192 + k * 64 + cp * 2];
                const float4 ya = *(const float4*)&A[k * 17 + eg * 8];
                const float4 yb = *(const float4*)&A[k * 17 + eg * 8 + 4];
                a0[0] += ya.x * wv.x; a1[0] += ya.x * wv.y;
                a0[1] += ya.y * wv.x; a1[1] += ya.y * wv.y;
                a0[2] += ya.z * wv.x; a1[2] += ya.z * wv.y;
                a0[3] += ya.w * wv.x; a1[3] += ya.w * wv.y;
                a0[4] += yb.x * wv.x; a1[4] += yb.x * wv.y;
                a0[5] += yb.y * wv.x; a1[5] += yb.y * wv.y;
                a0[6] += yb.z * wv.x; a1[6] += yb.z * wv.y;
                a0[7] += yb.w * wv.x; a1[7] += yb.w * wv.y;
            }
            const float2 b2 = *(const float2*)&wl[4288 + cp * 2];
#pragma unroll
            for (int b = 0; b < 8; ++b) { a0[b] = lrelu(a0[b] + b2.x); a1[b] = lrelu(a1[b] + b2.y); }
            *(float4*)&B[(cp * 2 + 0) * 17 + eg * 8]     = float4{a0[0], a0[1], a0[2], a0[3]};
            *(float4*)&B[(cp * 2 + 0) * 17 + eg * 8 + 4] = float4{a0[4], a0[5], a0[6], a0[7]};
            *(float4*)&B[(cp * 2 + 1) * 17 + eg * 8]     = float4{a1[0], a1[1], a1[2], a1[3]};
            *(float4*)&B[(cp * 2 + 1) * 17 + eg * 8 + 4] = float4{a1[4], a1[5], a1[6], a1[7]};
        }

        // ---- e-L3: 64 -> 16 (no act) -> zf Z[k][b] stride 9 ----
        {
            float a[4] = {0, 0, 0, 0};
#pragma unroll 8
            for (int k = 0; k < 64; ++k) {
                const float yv = B[k * 17 + ev];
                const float4 wv = *(const float4*)&wl[4352 + k * 16 + cg * 4];
                a[0] += yv * wv.x; a[1] += yv * wv.y;
                a[2] += yv * wv.z; a[3] += yv * wv.w;
            }
            const float4 b3 = *(const float4*)&wl[5376 + cg * 4];
            const int sg = ev >> 3, b = ev & 7;
#pragma unroll
            for (int i = 0; i < 4; ++i)
                Z[(sg * 16 + cg * 4 + i) * 9 + b] = a[i] + (&b3.x)[i];
        }

        // ---- f-L1: 32 -> 128 (leaky) -> B as sF[k][b] stride 9 ----
        {
            float a0[8] = {0, 0, 0, 0, 0, 0, 0, 0};
            float a1[8] = {0, 0, 0, 0, 0, 0, 0, 0};
#pragma unroll 4
            for (int k = 0; k < 32; ++k) {
                const float2 wv = *(const float2*)&wl[5392 + k * 128 + fcp * 2];
                const float4 ya = *(const float4*)&Z[k * 9];
                const float4 yb = *(const float4*)&Z[k * 9 + 4];
                a0[0] += ya.x * wv.x; a1[0] += ya.x * wv.y;
                a0[1] += ya.y * wv.x; a1[1] += ya.y * wv.y;
                a0[2] += ya.z * wv.x; a1[2] += ya.z * wv.y;
                a0[3] += ya.w * wv.x; a1[3] += ya.w * wv.y;
                a0[4] += yb.x * wv.x; a1[4] += yb.x * wv.y;
                a0[5] += yb.y * wv.x; a1[5] += yb.y * wv.y;
                a0[6] += yb.z * wv.x; a1[6] += yb.z * wv.y;
                a0[7] += yb.w * wv.x; a1[7] += yb.w * wv.y;
            }
            const float2 b1 = *(const float2*)&wl[9488 + fcp * 2];
#pragma unroll
            for (int b = 0; b < 8; ++b) { a0[b] = lrelu(a0[b] + b1.x); a1[b] = lrelu(a1[b] + b1.y); }
            *(float4*)&B[(fcp * 2 + 0) * 9]     = float4{a0[0], a0[1], a0[2], a0[3]};
            *(float4*)&B[(fcp * 2 + 0) * 9 + 4] = float4{a0[4], a0[5], a0[6], a0[7]};
            *(float4*)&B[(fcp * 2 + 1) * 9]     = float4{a1[0], a1[1], a1[2], a1[3]};
            *(float4*)&B[(fcp * 2 + 1) * 9 + 4] = float4{a1[4], a1[5], a1[6], a1[7]};
        }

        // ---- f-L2: 128 -> 128 (leaky) -> A as sG2[b][k] stride 132 ----
        {
            float a0[8] = {0, 0, 0, 0, 0, 0, 0, 0};
            float a1[8] = {0, 0, 0, 0, 0, 0, 0, 0};
#pragma unroll 4
            for (int k = 0; k < 128; ++k) {
                const float2 wv = *(const float2*)&wl[9616 + k * 128 + fcp * 2];
                const float4 ya = *(const float4*)&B[k * 9];
                const float4 yb = *(const float4*)&B[k * 9 + 4];
                a0[0] += ya.x * wv.x; a1[0] += ya.x * wv.y;
                a0[1] += ya.y * wv.x; a1[1] += ya.y * wv.y;
                a0[2] += ya.z * wv.x; a1[2] += ya.z * wv.y;
                a0[3] += ya.w * wv.x; a1[3] += ya.w * wv.y;
                a0[4] += yb.x * wv.x; a1[4] += yb.x * wv.y;
                a0[5] += yb.y * wv.x; a1[5] += yb.y * wv.y;
                a0[6] += yb.z * wv.x; a1[6] += yb.z * wv.y;
                a0[7] += yb.w * wv.x; a1[7] += yb.w * wv.y;
            }
            const float2 b2 = *(const float2*)&wl[26000 + fcp * 2];
#pragma unroll
            for (int b = 0; b < 8; ++b) {
                A[b * 132 + fcp * 2 + 0] = lrelu(a0[b] + b2.x);
                A[b * 132 + fcp * 2 + 1] = lrelu(a1[b] + b2.y);
            }
        }

        // ---- f-L3: 128 -> 8 (no act) + sin/cos epilogue ----
        {
            float a = 0.f;
#pragma unroll 8
            for (int k4 = 0; k4 < 32; ++k4) {
                const float4 y = *(const float4*)&A[fb * 132 + k4 * 4];
                const float4 wv = *(const float4*)&wl[26128 + fc * 128 + k4 * 4];
                a += y.x * wv.x + y.y * wv.y + y.z * wv.z + y.w * wv.w;
            }
            a += wl[27152 + fc];
            const int kk = q + fb;
            if (kk < cntq) {
                const int bi = perm[base + k0 + kk];
                out[(size_t)bi * 16 + fc]     = __sinf(a);
                out[(size_t)bi * 16 + 8 + fc] = __cosf(a);
            }
        }
    }
}

// ---------------------------------------------------------------------------
extern "C" void kernel_launch(void* const* d_in, const int* in_sizes, int n_in,
                              void* d_out, int out_size, void* d_ws, size_t ws_size,
                              hipStream_t stream)
{
    const int*   indices = (const int*)  d_in[0];
    const float* states  = (const float*)d_in[1];
    const float* maps    = (const float*)d_in[2];
    const float* fc1_w   = (const float*)d_in[3];
    const float* fc1_b   = (const float*)d_in[4];
    const float* fc2_w   = (const float*)d_in[5];
    const float* fc2_b   = (const float*)d_in[6];
    const float* fc3_w   = (const float*)d_in[7];
    const float* fc3_b   = (const float*)d_in[8];
    const float* bn_w    = (const float*)d_in[9];
    const float* bn_b    = (const float*)d_in[10];
    const float* e_w     = (const float*)d_in[11];
    const float* e_b     = (const float*)d_in[12];
    const float* f_w     = (const float*)d_in[13];
    const float* f_b     = (const float*)d_in[14];
    float* out = (float*)d_out;

    float* ws   = (float*)d_ws;
    float* z    = ws;                    // 2048
    float* th_e = ws + 2048;             // 349184
    float* th_f = ws + 351232;           // 1393152
    int* counts  = (int*)(ws + 1744384); // 64
    int* offsets = counts + 64;          // 64
    int* perm    = counts + 128;         // 8192

    backbone_bucket_kernel<<<65, 1024, 0, stream>>>(
        maps, fc1_w, fc1_b, fc2_w, fc2_b, fc3_w, fc3_b, bn_w, bn_b, z,
        indices, counts, offsets, perm);
    theta_kernel<<<dim3(107, 8), 256, 0, stream>>>(
        z, e_w, e_b, f_w, f_b, th_e, th_f);
    func_kernel<<<dim3(NCLS, NSLICE), 256, 0, stream>>>(
        states, th_e, th_f, counts, offsets, perm, out);
}